// Round 1
// baseline (310.781 us; speedup 1.0000x reference)
//
#include <hip/hip_runtime.h>
#include <math.h>

// Problem constants
#define Bn 16
#define Qn 64
#define Nn 16384
#define Dn 128
#define NT 128                  // n-tile per k_logits block
#define NTILES (Nn / NT)        // 128
#define NCHUNK 256              // n per k_pv block (was 512; halved for 4 blocks/CU)
#define NCHUNKS (Nn / NCHUNK)   // 64

#define RES_ELEMS  (Bn * Qn * Dn)      // 131072
#define SOFT_OFF   (RES_ELEMS)
#define LOG_OFF    (RES_ELEMS + Bn * Qn * Nn)

#define NEGF (-3.4e38f)

typedef __attribute__((ext_vector_type(8))) short short8;   // 8 bf16 (4 VGPRs)
typedef float f32x4 __attribute__((ext_vector_type(4)));    // MFMA accumulator

typedef union { unsigned int u[4]; short8 v; } pk8;

// round-to-nearest-even fp32 -> bf16 (inputs are finite randn; no NaN path)
__device__ __forceinline__ unsigned short f2bf(float x) {
    unsigned int u = __float_as_uint(x);
    return (unsigned short)((u + 0x7FFF + ((u >> 16) & 1)) >> 16);
}
__device__ __forceinline__ float bf2f(unsigned short h) {
    return __uint_as_float(((unsigned int)h) << 16);
}

// Swizzled u16 index in a [rows][64]-u16 plane: XOR col bits 3..5 with row bits 0..2.
// Keeps ushort4 (8B) writes and short8 (16B) reads aligned; bank-balanced both ways.
__device__ __forceinline__ int swz(int row, int col) {
    return row * 64 + (col ^ ((row & 7) << 3));
}

// ---------------------------------------------------------------------------
// K1: logits = Q @ A^T via split-bf16 MFMA (hi*hi + hi*lo + lo*hi == fp32-ish)
// Block: 256 thr = 4 waves. Tile M=64 q x N=128 n, K=128 in 2 chunks of 64.
// LDS 48 KB (pitch-64 + XOR swizzle) -> 3 blocks/CU. Second k-chunk's global
// loads are register-prefetched under the first chunk's MFMA phase (T14).
// Epilogue: acc -> LDS (fp32) -> coalesced float4 logits stores + masked stats.
// ---------------------------------------------------------------------------
__global__ __launch_bounds__(256, 3) void k_logits(
    const float* __restrict__ qv, const float* __restrict__ A,
    const int* __restrict__ nodeNum,
    float* __restrict__ logits,
    float* __restrict__ pmax, float* __restrict__ psum)
{
    const int b = blockIdx.y, tile = blockIdx.x;
    const int n0 = tile * NT;
    const int tid = threadIdx.x;
    const int lane = tid & 63, wave = tid >> 6;
    const int qd = lane >> 4, cc = lane & 15;   // quad, col-in-16

    // staging (phase 1): QHI/QLO 64x64 u16, AHI/ALO 128x64 u16 = 49152 B (swizzled)
    // alias (phase 2): CB 64x132 f32 (33792 B), REDM/REDS 64x17 f32
    __shared__ __align__(16) unsigned char smem[49152];
    unsigned short* QHI = (unsigned short*)smem;
    unsigned short* QLO = QHI + 64 * 64;
    unsigned short* AHI = QLO + 64 * 64;
    unsigned short* ALO = AHI + 128 * 64;
    float* CB   = (float*)smem;            // [64][132]
    float* REDM = ((float*)smem) + 64 * 132;
    float* REDS = REDM + 64 * 17;

    f32x4 acc[4][2];
#pragma unroll
    for (int mi = 0; mi < 4; mi++)
#pragma unroll
        for (int ni = 0; ni < 2; ni++) acc[mi][ni] = 0.f;

    const float* qb = qv + (size_t)b * Qn * Dn;
    const float* Ab = A  + (size_t)b * Nn * Dn + (size_t)n0 * Dn;

    const int r16 = tid >> 4, c4 = tid & 15;    // staging row-base / float4 col

    float4 qreg[4], areg[8];

    auto loadQ = [&](int kk) {
#pragma unroll
        for (int t = 0; t < 4; t++)
            qreg[t] = *(const float4*)(qb + (size_t)(r16 + 16 * t) * Dn + kk + c4 * 4);
    };
    auto loadA = [&](int kk) {
#pragma unroll
        for (int t = 0; t < 8; t++)
            areg[t] = *(const float4*)(Ab + (size_t)(r16 + 16 * t) * Dn + kk + c4 * 4);
    };
    auto cvtWrite = [&]() {
#pragma unroll
        for (int t = 0; t < 4; t++) {
            int row = r16 + 16 * t;
            float4 v = qreg[t];
            ushort4 hi, lo;
            hi.x = f2bf(v.x); lo.x = f2bf(v.x - bf2f(hi.x));
            hi.y = f2bf(v.y); lo.y = f2bf(v.y - bf2f(hi.y));
            hi.z = f2bf(v.z); lo.z = f2bf(v.z - bf2f(hi.z));
            hi.w = f2bf(v.w); lo.w = f2bf(v.w - bf2f(hi.w));
            int idx = swz(row, c4 * 4);
            *(ushort4*)(QHI + idx) = hi;
            *(ushort4*)(QLO + idx) = lo;
        }
#pragma unroll
        for (int t = 0; t < 8; t++) {
            int row = r16 + 16 * t;
            float4 v = areg[t];
            ushort4 hi, lo;
            hi.x = f2bf(v.x); lo.x = f2bf(v.x - bf2f(hi.x));
            hi.y = f2bf(v.y); lo.y = f2bf(v.y - bf2f(hi.y));
            hi.z = f2bf(v.z); lo.z = f2bf(v.z - bf2f(hi.z));
            hi.w = f2bf(v.w); lo.w = f2bf(v.w - bf2f(hi.w));
            int idx = swz(row, c4 * 4);
            *(ushort4*)(AHI + idx) = hi;
            *(ushort4*)(ALO + idx) = lo;
        }
    };
    auto compute = [&]() {
#pragma unroll
        for (int ks = 0; ks < 64; ks += 32) {
            const int ko = ks + qd * 8;   // u16 col of this lane's k-octet
            short8 qh[4], ql[4], ah[2], al[2];
#pragma unroll
            for (int mi = 0; mi < 4; mi++) {
                int r = mi * 16 + cc;
                int idx = swz(r, ko);
                qh[mi] = *(const short8*)(QHI + idx);
                ql[mi] = *(const short8*)(QLO + idx);
            }
#pragma unroll
            for (int ni = 0; ni < 2; ni++) {
                int r = (wave * 2 + ni) * 16 + cc;
                int idx = swz(r, ko);
                ah[ni] = *(const short8*)(AHI + idx);
                al[ni] = *(const short8*)(ALO + idx);
            }
#pragma unroll
            for (int mi = 0; mi < 4; mi++)
#pragma unroll
                for (int ni = 0; ni < 2; ni++) {
                    acc[mi][ni] = __builtin_amdgcn_mfma_f32_16x16x32_bf16(
                        ql[mi], ah[ni], acc[mi][ni], 0, 0, 0);
                    acc[mi][ni] = __builtin_amdgcn_mfma_f32_16x16x32_bf16(
                        qh[mi], al[ni], acc[mi][ni], 0, 0, 0);
                    acc[mi][ni] = __builtin_amdgcn_mfma_f32_16x16x32_bf16(
                        qh[mi], ah[ni], acc[mi][ni], 0, 0, 0);
                }
        }
    };

    // kk = 0: load + convert + write
    loadQ(0); loadA(0);
    cvtWrite();
    __syncthreads();
    // prefetch kk = 64 into registers, then compute kk = 0 on top of it
    loadQ(64); loadA(64);
    compute();
    __syncthreads();
    // kk = 64: convert prefetched regs + write, then compute
    cvtWrite();
    __syncthreads();
    compute();

    __syncthreads();   // staging dead; alias LDS as CB
    // C-layout: col = lane&15 (n), row = quad*4 + reg (q)
#pragma unroll
    for (int mi = 0; mi < 4; mi++)
#pragma unroll
        for (int ni = 0; ni < 2; ni++)
#pragma unroll
            for (int r = 0; r < 4; r++) {
                int q = mi * 16 + qd * 4 + r;
                int n = (wave * 2 + ni) * 16 + cc;
                CB[q * 132 + n] = acc[mi][ni][r];
            }
    __syncthreads();

    const int nv = nodeNum[b];
    // coalesced logits store
#pragma unroll
    for (int t = 0; t < 8; t++) {
        int u = tid + t * 256;
        int q = u >> 5, ng = u & 31;
        float4 v = *(const float4*)(CB + q * 132 + ng * 4);
        *(float4*)(logits + ((size_t)(b * Qn + q)) * Nn + n0 + ng * 4) = v;
    }
    // masked per-tile stats
#pragma unroll
    for (int t = 0; t < 4; t++) {
        int u = tid + t * 256;
        int q = u >> 4, c = u & 15;
        const float* base = CB + q * 132 + c * 8;
        float m = NEGF;
#pragma unroll
        for (int j = 0; j < 8; j++)
            if (n0 + c * 8 + j < nv) m = fmaxf(m, base[j]);
        float s = 0.f;
#pragma unroll
        for (int j = 0; j < 8; j++)
            if (n0 + c * 8 + j < nv) s += __expf(base[j] - m);
        REDM[q * 17 + c] = m;
        REDS[q * 17 + c] = s;
    }
    __syncthreads();
    if (tid < Qn) {
        int q = tid;
        float M = NEGF;
#pragma unroll
        for (int t = 0; t < 16; t++) M = fmaxf(M, REDM[q * 17 + t]);
        float S = 0.f;
#pragma unroll
        for (int t = 0; t < 16; t++)
            S += REDS[q * 17 + t] * __expf(REDM[q * 17 + t] - M);
        pmax[((size_t)(b * Qn + q)) * NTILES + tile] = M;
        psum[((size_t)(b * Qn + q)) * NTILES + tile] = S;
    }
}

// ---------------------------------------------------------------------------
// K2: combine 128 per-tile partials per (b,q) row -> M, 1/L
// ---------------------------------------------------------------------------
__global__ __launch_bounds__(64) void k_rows(
    const float* __restrict__ pmax, const float* __restrict__ psum,
    float* __restrict__ Mrow, float* __restrict__ invL)
{
    const int row = blockIdx.x;
    const int t = threadIdx.x;
    const float* pm = pmax + (size_t)row * NTILES;
    const float* ps = psum + (size_t)row * NTILES;
    float m0 = pm[t], m1 = pm[t + 64];
    float s0 = ps[t], s1 = ps[t + 64];
    float m = fmaxf(m0, m1);
#pragma unroll
    for (int o = 32; o >= 1; o >>= 1) m = fmaxf(m, __shfl_xor(m, o, 64));
    float s = s0 * __expf(m0 - m) + s1 * __expf(m1 - m);
#pragma unroll
    for (int o = 32; o >= 1; o >>= 1) s += __shfl_xor(s, o, 64);
    if (t == 0) { Mrow[row] = m; invL[row] = 1.0f / s; }
}

// ---------------------------------------------------------------------------
// K3: softmax (p -> prob_soft fp32 + bf16 P-tile in LDS) then P @ A via MFMA.
// NCHUNK=256 -> 1024 blocks = 4/CU. Async-stage split (T14): slab s+1's
// logits/A global loads are issued between slab s's LDS write and its compute
// barrier, so L3/HBM latency hides under the MFMA phase.
// ---------------------------------------------------------------------------
__global__ __launch_bounds__(256, 4) void k_pv(
    const float* __restrict__ A, const int* __restrict__ nodeNum,
    const float* __restrict__ logits,
    const float* __restrict__ Mrow, const float* __restrict__ invL,
    float* __restrict__ soft, float* __restrict__ partial)
{
    const int b = blockIdx.y, chunk = blockIdx.x;
    const int tid = threadIdx.x;
    const int lane = tid & 63, wave = tid >> 6;
    const int qd = lane >> 4, cc = lane & 15;

    __shared__ __align__(16) unsigned short PS[64 * 40];   // P bf16 [q][32n], pitch 40
    __shared__ __align__(16) unsigned int  TMP2[16 * 132]; // A pairs [n2][128d], pitch 132
    __shared__ float MS[64], LS[64];

    if (tid < Qn) {
        MS[tid] = Mrow[b * Qn + tid];
        LS[tid] = invL[b * Qn + tid];
    }

    f32x4 acc[4][2];
#pragma unroll
    for (int mi = 0; mi < 4; mi++)
#pragma unroll
        for (int ni = 0; ni < 2; ni++) acc[mi][ni] = 0.f;

    const int nv = nodeNum[b];
    const float* Abase = A + (size_t)b * Nn * Dn;

    const int q0 = tid >> 3, ngc = tid & 7;     // softmax unit coords
    const int n20 = tid >> 5, db = tid & 31;    // A-stage unit coords

    float4 l4r[2], a0r[2], a1r[2];

    auto issue = [&](int s) {
        const int n0 = chunk * NCHUNK + s * 32;
#pragma unroll
        for (int t = 0; t < 2; t++) {
            int q = q0 + 32 * t;
            l4r[t] = *(const float4*)(logits + ((size_t)(b * Qn + q)) * Nn + n0 + ngc * 4);
        }
#pragma unroll
        for (int t = 0; t < 2; t++) {
            const float* r0 = Abase + (size_t)(n0 + (n20 + 8 * t) * 2) * Dn + db * 4;
            a0r[t] = *(const float4*)r0;          // n even
            a1r[t] = *(const float4*)(r0 + Dn);   // n odd
        }
    };

    issue(0);

    for (int s = 0; s < NCHUNK / 32; s++) {
        const int n0 = chunk * NCHUNK + s * 32;
        __syncthreads();   // PS/TMP2 reuse fence (and MS/LS on first iter)

        // softmax from prefetched regs: 64q x 32n
#pragma unroll
        for (int t = 0; t < 2; t++) {
            int q = q0 + 32 * t;
            size_t go = ((size_t)(b * Qn + q)) * Nn + n0 + ngc * 4;
            float4 l4 = l4r[t];
            float mq = MS[q], iq = LS[q];
            int nb = n0 + ngc * 4;
            float4 p;
            p.x = (nb + 0 < nv) ? __expf(l4.x - mq) * iq : 0.f;
            p.y = (nb + 1 < nv) ? __expf(l4.y - mq) * iq : 0.f;
            p.z = (nb + 2 < nv) ? __expf(l4.z - mq) * iq : 0.f;
            p.w = (nb + 3 < nv) ? __expf(l4.w - mq) * iq : 0.f;
            *(float4*)(soft + go) = p;
            unsigned int d0 = (unsigned)f2bf(p.x) | ((unsigned)f2bf(p.y) << 16);
            unsigned int d1 = (unsigned)f2bf(p.z) | ((unsigned)f2bf(p.w) << 16);
            unsigned int* dst = (unsigned int*)(PS + q * 40 + ngc * 4);
            dst[0] = d0; dst[1] = d1;
        }
        // pack prefetched A slab as (n,n+1) bf16 pairs
#pragma unroll
        for (int t = 0; t < 2; t++) {
            int n2 = n20 + 8 * t;
            float4 a0 = a0r[t], a1 = a1r[t];
            uint4 w;
            w.x = (unsigned)f2bf(a0.x) | ((unsigned)f2bf(a1.x) << 16);
            w.y = (unsigned)f2bf(a0.y) | ((unsigned)f2bf(a1.y) << 16);
            w.z = (unsigned)f2bf(a0.z) | ((unsigned)f2bf(a1.z) << 16);
            w.w = (unsigned)f2bf(a0.w) | ((unsigned)f2bf(a1.w) << 16);
            *(uint4*)(TMP2 + n2 * 132 + db * 4) = w;
        }
        // async-stage: issue next slab's global loads before the compute barrier
        if (s + 1 < NCHUNK / 32) issue(s + 1);
        __syncthreads();

        short8 pf[4];
#pragma unroll
        for (int mi = 0; mi < 4; mi++)
            pf[mi] = *(const short8*)(PS + (mi * 16 + cc) * 40 + qd * 8);
#pragma unroll
        for (int ni = 0; ni < 2; ni++) {
            int d = (wave * 2 + ni) * 16 + cc;
            pk8 bfr;
#pragma unroll
            for (int j = 0; j < 4; j++)
                bfr.u[j] = TMP2[(qd * 4 + j) * 132 + d];
#pragma unroll
            for (int mi = 0; mi < 4; mi++)
                acc[mi][ni] = __builtin_amdgcn_mfma_f32_16x16x32_bf16(
                    pf[mi], bfr.v, acc[mi][ni], 0, 0, 0);
        }
    }

    float* pout = partial + (size_t)chunk * RES_ELEMS + (size_t)(b * Qn) * Dn;
#pragma unroll
    for (int mi = 0; mi < 4; mi++)
#pragma unroll
        for (int ni = 0; ni < 2; ni++)
#pragma unroll
            for (int r = 0; r < 4; r++) {
                int q = mi * 16 + qd * 4 + r;
                int d = (wave * 2 + ni) * 16 + cc;
                pout[q * Dn + d] = acc[mi][ni][r];
            }
}

// ---------------------------------------------------------------------------
// K4: res = sum over 64 chunk-partials
// ---------------------------------------------------------------------------
__global__ __launch_bounds__(256) void k_red(
    const float* __restrict__ partial, float* __restrict__ res)
{
    int g = blockIdx.x * 256 + threadIdx.x;
    float s = 0.f;
#pragma unroll
    for (int t = 0; t < NCHUNKS; t++)
        s += partial[(size_t)t * RES_ELEMS + g];
    res[g] = s;
}

extern "C" void kernel_launch(void* const* d_in, const int* in_sizes, int n_in,
                              void* d_out, int out_size, void* d_ws, size_t ws_size,
                              hipStream_t stream) {
    const float* qv = (const float*)d_in[0];
    const float* A  = (const float*)d_in[1];
    const int*   nn = (const int*)d_in[2];

    float* out    = (float*)d_out;
    float* res    = out;
    float* soft   = out + SOFT_OFF;
    float* logits = out + LOG_OFF;

    float* ws      = (float*)d_ws;
    float* pmax    = ws;
    float* psum    = pmax + (size_t)Bn * Qn * NTILES;
    float* Mrow    = psum + (size_t)Bn * Qn * NTILES;
    float* invL    = Mrow + Bn * Qn;
    float* partial = invL + Bn * Qn;

    dim3 blk(256);
    k_logits<<<dim3(NTILES, Bn), blk, 0, stream>>>(qv, A, nn, logits, pmax, psum);
    k_rows<<<Bn * Qn, 64, 0, stream>>>(pmax, psum, Mrow, invL);
    k_pv<<<dim3(NCHUNKS, Bn), blk, 0, stream>>>(A, nn, logits, Mrow, invL, soft, partial);
    k_red<<<RES_ELEMS / 256, blk, 0, stream>>>(partial, res);
}

// Round 2
// 289.990 us; speedup vs baseline: 1.0717x; 1.0717x over previous
//
#include <hip/hip_runtime.h>
#include <math.h>

// Problem constants
#define Bn 16
#define Qn 64
#define Nn 16384
#define Dn 128
#define NT 128                  // n-tile per k_logits block
#define NTILES (Nn / NT)        // 128
#define NCHUNK 256              // n per k_pv block -> grid 1024 = 4 blocks/CU
#define NCHUNKS (Nn / NCHUNK)   // 64

#define RES_ELEMS  (Bn * Qn * Dn)      // 131072
#define SOFT_OFF   (RES_ELEMS)
#define LOG_OFF    (RES_ELEMS + Bn * Qn * Nn)

#define NEGF (-3.4e38f)

typedef __attribute__((ext_vector_type(8))) short short8;   // 8 bf16 (4 VGPRs)
typedef float f32x4 __attribute__((ext_vector_type(4)));    // MFMA accumulator

typedef union { unsigned int u[4]; short8 v; } pk8;

// HW packed f32->bf16 (RTNE): dst.lo16 = bf16(a), dst.hi16 = bf16(b)
__device__ __forceinline__ unsigned int cvt_pk_bf16(float a, float b) {
    unsigned int r;
    asm("v_cvt_pk_bf16_f32 %0, %1, %2" : "=v"(r) : "v"(a), "v"(b));
    return r;
}

// Swizzled u16 index in a [rows][64]-u16 plane: XOR col bits 3..5 with row bits 0..2.
// Keeps 8B writes and 16B reads aligned; bank-balanced both ways. (Verified R1.)
__device__ __forceinline__ int swz(int row, int col) {
    return row * 64 + (col ^ ((row & 7) << 3));
}

// ---------------------------------------------------------------------------
// K0: zero res (atomic accumulation target for k_pv)
// ---------------------------------------------------------------------------
__global__ __launch_bounds__(256) void k_zero(float* __restrict__ res)
{
    int g = blockIdx.x * 256 + threadIdx.x;
    float4 z; z.x = 0.f; z.y = 0.f; z.z = 0.f; z.w = 0.f;
    ((float4*)res)[g] = z;
}

// ---------------------------------------------------------------------------
// K1: logits = Q @ A^T via split-bf16 MFMA (hi*hi + hi*lo + lo*hi == fp32-ish)
// Block: 256 thr = 4 waves. Tile M=64 q x N=128 n, K=128 in 2 chunks of 64.
// LDS 48 KB (pitch-64 + XOR swizzle) -> 3 blocks/CU. Staging conversion uses
// v_cvt_pk_bf16_f32 (12 VALU per float4 vs ~36 scalar) -- staging was the
// VALU bottleneck (~860 cyc/wave/chunk vs 240 cyc MFMA).
// Epilogue: acc -> LDS (fp32) -> coalesced float4 logits stores + masked stats.
// ---------------------------------------------------------------------------
__global__ __launch_bounds__(256, 3) void k_logits(
    const float* __restrict__ qv, const float* __restrict__ A,
    const int* __restrict__ nodeNum,
    float* __restrict__ logits,
    float* __restrict__ pmax, float* __restrict__ psum)
{
    const int b = blockIdx.y, tile = blockIdx.x;
    const int n0 = tile * NT;
    const int tid = threadIdx.x;
    const int lane = tid & 63, wave = tid >> 6;
    const int qd = lane >> 4, cc = lane & 15;   // quad, col-in-16

    // staging (phase 1): QHI/QLO 64x64 u16, AHI/ALO 128x64 u16 = 49152 B (swizzled)
    // alias (phase 2): CB 64x132 f32 (33792 B), REDM/REDS 64x17 f32
    __shared__ __align__(16) unsigned char smem[49152];
    unsigned short* QHI = (unsigned short*)smem;
    unsigned short* QLO = QHI + 64 * 64;
    unsigned short* AHI = QLO + 64 * 64;
    unsigned short* ALO = AHI + 128 * 64;
    float* CB   = (float*)smem;            // [64][132]
    float* REDM = ((float*)smem) + 64 * 132;
    float* REDS = REDM + 64 * 17;

    f32x4 acc[4][2];
#pragma unroll
    for (int mi = 0; mi < 4; mi++)
#pragma unroll
        for (int ni = 0; ni < 2; ni++) acc[mi][ni] = 0.f;

    const float* qb = qv + (size_t)b * Qn * Dn;
    const float* Ab = A  + (size_t)b * Nn * Dn + (size_t)n0 * Dn;

    const int r16 = tid >> 4, c4 = tid & 15;    // staging row-base / float4 col

    for (int kk = 0; kk < Dn; kk += 64) {
        __syncthreads();
        // stage Q slab 64x64 (4 float4/thread) + A slab 128x64 (8 float4/thread)
#pragma unroll
        for (int t = 0; t < 4; t++) {
            int row = r16 + 16 * t;
            float4 v = *(const float4*)(qb + (size_t)row * Dn + kk + c4 * 4);
            unsigned int h01 = cvt_pk_bf16(v.x, v.y);
            unsigned int h23 = cvt_pk_bf16(v.z, v.w);
            float rx = v.x - __uint_as_float(h01 << 16);
            float ry = v.y - __uint_as_float(h01 & 0xFFFF0000u);
            float rz = v.z - __uint_as_float(h23 << 16);
            float rw = v.w - __uint_as_float(h23 & 0xFFFF0000u);
            unsigned int l01 = cvt_pk_bf16(rx, ry);
            unsigned int l23 = cvt_pk_bf16(rz, rw);
            int idx = swz(row, c4 * 4);
            uint2 hh; hh.x = h01; hh.y = h23;
            uint2 ll; ll.x = l01; ll.y = l23;
            *(uint2*)(QHI + idx) = hh;
            *(uint2*)(QLO + idx) = ll;
        }
#pragma unroll
        for (int t = 0; t < 8; t++) {
            int row = r16 + 16 * t;
            float4 v = *(const float4*)(Ab + (size_t)row * Dn + kk + c4 * 4);
            unsigned int h01 = cvt_pk_bf16(v.x, v.y);
            unsigned int h23 = cvt_pk_bf16(v.z, v.w);
            float rx = v.x - __uint_as_float(h01 << 16);
            float ry = v.y - __uint_as_float(h01 & 0xFFFF0000u);
            float rz = v.z - __uint_as_float(h23 << 16);
            float rw = v.w - __uint_as_float(h23 & 0xFFFF0000u);
            unsigned int l01 = cvt_pk_bf16(rx, ry);
            unsigned int l23 = cvt_pk_bf16(rz, rw);
            int idx = swz(row, c4 * 4);
            uint2 hh; hh.x = h01; hh.y = h23;
            uint2 ll; ll.x = l01; ll.y = l23;
            *(uint2*)(AHI + idx) = hh;
            *(uint2*)(ALO + idx) = ll;
        }
        __syncthreads();
#pragma unroll
        for (int ks = 0; ks < 64; ks += 32) {
            const int ko = ks + qd * 8;   // u16 col of this lane's k-octet
            short8 qh[4], ql[4], ah[2], al[2];
#pragma unroll
            for (int mi = 0; mi < 4; mi++) {
                int r = mi * 16 + cc;
                int idx = swz(r, ko);
                qh[mi] = *(const short8*)(QHI + idx);
                ql[mi] = *(const short8*)(QLO + idx);
            }
#pragma unroll
            for (int ni = 0; ni < 2; ni++) {
                int r = (wave * 2 + ni) * 16 + cc;
                int idx = swz(r, ko);
                ah[ni] = *(const short8*)(AHI + idx);
                al[ni] = *(const short8*)(ALO + idx);
            }
#pragma unroll
            for (int mi = 0; mi < 4; mi++)
#pragma unroll
                for (int ni = 0; ni < 2; ni++) {
                    acc[mi][ni] = __builtin_amdgcn_mfma_f32_16x16x32_bf16(
                        ql[mi], ah[ni], acc[mi][ni], 0, 0, 0);
                    acc[mi][ni] = __builtin_amdgcn_mfma_f32_16x16x32_bf16(
                        qh[mi], al[ni], acc[mi][ni], 0, 0, 0);
                    acc[mi][ni] = __builtin_amdgcn_mfma_f32_16x16x32_bf16(
                        qh[mi], ah[ni], acc[mi][ni], 0, 0, 0);
                }
        }
    }

    __syncthreads();   // staging dead; alias LDS as CB
    // C-layout: col = lane&15 (n), row = quad*4 + reg (q)
#pragma unroll
    for (int mi = 0; mi < 4; mi++)
#pragma unroll
        for (int ni = 0; ni < 2; ni++)
#pragma unroll
            for (int r = 0; r < 4; r++) {
                int q = mi * 16 + qd * 4 + r;
                int n = (wave * 2 + ni) * 16 + cc;
                CB[q * 132 + n] = acc[mi][ni][r];
            }
    __syncthreads();

    const int nv = nodeNum[b];
    // coalesced logits store
#pragma unroll
    for (int t = 0; t < 8; t++) {
        int u = tid + t * 256;
        int q = u >> 5, ng = u & 31;
        float4 v = *(const float4*)(CB + q * 132 + ng * 4);
        *(float4*)(logits + ((size_t)(b * Qn + q)) * Nn + n0 + ng * 4) = v;
    }
    // masked per-tile stats
#pragma unroll
    for (int t = 0; t < 4; t++) {
        int u = tid + t * 256;
        int q = u >> 4, c = u & 15;
        const float* base = CB + q * 132 + c * 8;
        float m = NEGF;
#pragma unroll
        for (int j = 0; j < 8; j++)
            if (n0 + c * 8 + j < nv) m = fmaxf(m, base[j]);
        float s = 0.f;
#pragma unroll
        for (int j = 0; j < 8; j++)
            if (n0 + c * 8 + j < nv) s += __expf(base[j] - m);
        REDM[q * 17 + c] = m;
        REDS[q * 17 + c] = s;
    }
    __syncthreads();
    if (tid < Qn) {
        int q = tid;
        float M = NEGF;
#pragma unroll
        for (int t = 0; t < 16; t++) M = fmaxf(M, REDM[q * 17 + t]);
        float S = 0.f;
#pragma unroll
        for (int t = 0; t < 16; t++)
            S += REDS[q * 17 + t] * __expf(REDM[q * 17 + t] - M);
        pmax[((size_t)(b * Qn + q)) * NTILES + tile] = M;
        psum[((size_t)(b * Qn + q)) * NTILES + tile] = S;
    }
}

// ---------------------------------------------------------------------------
// K2: combine 128 per-tile partials per (b,q) row -> M, 1/L
// ---------------------------------------------------------------------------
__global__ __launch_bounds__(64) void k_rows(
    const float* __restrict__ pmax, const float* __restrict__ psum,
    float* __restrict__ Mrow, float* __restrict__ invL)
{
    const int row = blockIdx.x;
    const int t = threadIdx.x;
    const float* pm = pmax + (size_t)row * NTILES;
    const float* ps = psum + (size_t)row * NTILES;
    float m0 = pm[t], m1 = pm[t + 64];
    float s0 = ps[t], s1 = ps[t + 64];
    float m = fmaxf(m0, m1);
#pragma unroll
    for (int o = 32; o >= 1; o >>= 1) m = fmaxf(m, __shfl_xor(m, o, 64));
    float s = s0 * __expf(m0 - m) + s1 * __expf(m1 - m);
#pragma unroll
    for (int o = 32; o >= 1; o >>= 1) s += __shfl_xor(s, o, 64);
    if (t == 0) { Mrow[row] = m; invL[row] = 1.0f / s; }
}

// ---------------------------------------------------------------------------
// K3: softmax (p -> prob_soft fp32 + bf16 P-tile in LDS) then P @ A via MFMA.
// NCHUNK=256 -> grid 1024 = 4 blocks/CU (was grid-capped at 2/CU).
// Epilogue accumulates into res via atomicAdd (res pre-zeroed by k_zero) --
// removes the partial buffer (2x 17-33 MB traffic) and the k_red kernel.
// ---------------------------------------------------------------------------
__global__ __launch_bounds__(256, 4) void k_pv(
    const float* __restrict__ A, const int* __restrict__ nodeNum,
    const float* __restrict__ logits,
    const float* __restrict__ Mrow, const float* __restrict__ invL,
    float* __restrict__ soft, float* __restrict__ res)
{
    const int b = blockIdx.y, chunk = blockIdx.x;
    const int tid = threadIdx.x;
    const int lane = tid & 63, wave = tid >> 6;
    const int qd = lane >> 4, cc = lane & 15;

    __shared__ __align__(16) unsigned short PS[64 * 40];   // P bf16 [q][32n], pitch 40
    __shared__ __align__(16) unsigned int  TMP2[16 * 132]; // A pairs [n2][128d], pitch 132
    __shared__ float MS[64], LS[64];

    if (tid < Qn) {
        MS[tid] = Mrow[b * Qn + tid];
        LS[tid] = invL[b * Qn + tid];
    }

    f32x4 acc[4][2];
#pragma unroll
    for (int mi = 0; mi < 4; mi++)
#pragma unroll
        for (int ni = 0; ni < 2; ni++) acc[mi][ni] = 0.f;

    const int nv = nodeNum[b];
    const float* Abase = A + (size_t)b * Nn * Dn;

    for (int s = 0; s < NCHUNK / 32; s++) {
        const int n0 = chunk * NCHUNK + s * 32;
        __syncthreads();   // PS/TMP2 reuse fence (and MS/LS on first iter)

        // softmax: 64q x 32n = 512 float4-units of 4 n
#pragma unroll
        for (int t = 0; t < 2; t++) {
            int u = tid + t * 256;
            int q = u >> 3, ng = u & 7;
            size_t go = ((size_t)(b * Qn + q)) * Nn + n0 + ng * 4;
            float4 l4 = *(const float4*)(logits + go);
            float mq = MS[q], iq = LS[q];
            int nb = n0 + ng * 4;
            float4 p;
            p.x = (nb + 0 < nv) ? __expf(l4.x - mq) * iq : 0.f;
            p.y = (nb + 1 < nv) ? __expf(l4.y - mq) * iq : 0.f;
            p.z = (nb + 2 < nv) ? __expf(l4.z - mq) * iq : 0.f;
            p.w = (nb + 3 < nv) ? __expf(l4.w - mq) * iq : 0.f;
            *(float4*)(soft + go) = p;
            unsigned int* dst = (unsigned int*)(PS + q * 40 + ng * 4);
            dst[0] = cvt_pk_bf16(p.x, p.y);
            dst[1] = cvt_pk_bf16(p.z, p.w);
        }
        // stage A slab 32n x 128d as (n,n+1) bf16 pairs: 512 uint4-units
#pragma unroll
        for (int t = 0; t < 2; t++) {
            int u = tid + t * 256;
            int n2 = u >> 5, db = u & 31;
            const float* r0 = Abase + (size_t)(n0 + n2 * 2) * Dn + db * 4;
            float4 a0 = *(const float4*)r0;          // n even
            float4 a1 = *(const float4*)(r0 + Dn);   // n odd
            uint4 w;
            w.x = cvt_pk_bf16(a0.x, a1.x);
            w.y = cvt_pk_bf16(a0.y, a1.y);
            w.z = cvt_pk_bf16(a0.z, a1.z);
            w.w = cvt_pk_bf16(a0.w, a1.w);
            *(uint4*)(TMP2 + n2 * 132 + db * 4) = w;
        }
        __syncthreads();

        short8 pf[4];
#pragma unroll
        for (int mi = 0; mi < 4; mi++)
            pf[mi] = *(const short8*)(PS + (mi * 16 + cc) * 40 + qd * 8);
#pragma unroll
        for (int ni = 0; ni < 2; ni++) {
            int d = (wave * 2 + ni) * 16 + cc;
            pk8 bfr;
#pragma unroll
            for (int j = 0; j < 4; j++)
                bfr.u[j] = TMP2[(qd * 4 + j) * 132 + d];
#pragma unroll
            for (int mi = 0; mi < 4; mi++)
                acc[mi][ni] = __builtin_amdgcn_mfma_f32_16x16x32_bf16(
                    pf[mi], bfr.v, acc[mi][ni], 0, 0, 0);
        }
    }

    float* pout = res + (size_t)(b * Qn) * Dn;
#pragma unroll
    for (int mi = 0; mi < 4; mi++)
#pragma unroll
        for (int ni = 0; ni < 2; ni++)
#pragma unroll
            for (int r = 0; r < 4; r++) {
                int q = mi * 16 + qd * 4 + r;
                int d = (wave * 2 + ni) * 16 + cc;
                atomicAdd(&pout[q * Dn + d], acc[mi][ni][r]);
            }
}

extern "C" void kernel_launch(void* const* d_in, const int* in_sizes, int n_in,
                              void* d_out, int out_size, void* d_ws, size_t ws_size,
                              hipStream_t stream) {
    const float* qv = (const float*)d_in[0];
    const float* A  = (const float*)d_in[1];
    const int*   nn = (const int*)d_in[2];

    float* out    = (float*)d_out;
    float* res    = out;
    float* soft   = out + SOFT_OFF;
    float* logits = out + LOG_OFF;

    float* ws      = (float*)d_ws;
    float* pmax    = ws;
    float* psum    = pmax + (size_t)Bn * Qn * NTILES;
    float* Mrow    = psum + (size_t)Bn * Qn * NTILES;
    float* invL    = Mrow + Bn * Qn;

    dim3 blk(256);
    k_zero<<<RES_ELEMS / 1024, blk, 0, stream>>>(res);
    k_logits<<<dim3(NTILES, Bn), blk, 0, stream>>>(qv, A, nn, logits, pmax, psum);
    k_rows<<<Bn * Qn, 64, 0, stream>>>(pmax, psum, Mrow, invL);
    k_pv<<<dim3(NCHUNKS, Bn), blk, 0, stream>>>(A, nn, logits, Mrow, invL, soft, res);
}